// Round 8
// baseline (109.028 us; speedup 1.0000x reference)
//
#include <hip/hip_runtime.h>

#define B_DIM 256
#define IN_DIM 512
#define OUT_DIM 1024

// ---------- bit decode: [8] spike bits -> fp32 (exact E4M3 value) ----------
__device__ __forceinline__ float dec_pair(float4 a, float4 b) {
    int ef  = ((int)a.y << 3) | ((int)a.z << 2) | ((int)a.w << 1) | (int)b.x;
    int man = ((int)b.y << 2) | ((int)b.z << 1) | (int)b.w;
    float mag;
    if (ef > 0)
        mag = __uint_as_float(((unsigned)(ef + 120) << 23) | ((unsigned)man << 20));
    else
        mag = (float)man * 0.001953125f;  // man * 2^-9 (subnormal)
    return (a.x != 0.0f) ? -mag : mag;
}

// One dispatch decodes both x (v < 131072) and w (rest). Branch is uniform
// per block (131072 = 512 full blocks).
__global__ void k_decode(const float* __restrict__ xbits,
                         const float* __restrict__ wbits,
                         float* __restrict__ xf, float* __restrict__ wt) {
    int v = blockIdx.x * 256 + threadIdx.x;          // 0 .. 655359
    if (v < B_DIM * IN_DIM) {
        const float4* p = (const float4*)xbits + (size_t)v * 2;
        xf[v] = dec_pair(p[0], p[1]);
    } else {
        int u = v - B_DIM * IN_DIM;
        const float4* p = (const float4*)wbits + (size_t)u * 2;
        float val = dec_pair(p[0], p[1]);
        int o = u >> 9, i = u & 511;
        // wt layout [(i>>2)][o][i&3]: one coalesced dwordx4 per 4 K-steps in k_main
        wt[((size_t)(i >> 2) * OUT_DIM + o) * 4 + (i & 3)] = val;
    }
}

// ---------- encode fp32 (exact E4M3) -> [8] spike bits ----------
__device__ __forceinline__ void store8(float* __restrict__ out, int idx, float v) {
    unsigned au = __float_as_uint(v) & 0x7fffffffu;
    float sgn = (v < 0.0f) ? 1.0f : 0.0f;           // -0.0 -> sign bit 0, like ref
    int ef, man;
    if (au >= 0x3c800000u) {                         // |v| >= 2^-6 : normal
        ef  = (int)(au >> 23) - 120;                 // (exp-127)+7
        man = (int)((au >> 20) & 7u);
    } else {                                         // subnormal / zero
        ef  = 0;
        man = (int)(__uint_as_float(au) * 512.0f);   // exact multiple of 2^-9
    }
    float4 lo = make_float4(sgn,
                            (float)((ef >> 3) & 1), (float)((ef >> 2) & 1),
                            (float)((ef >> 1) & 1));
    float4 hi = make_float4((float)(ef & 1),
                            (float)((man >> 2) & 1), (float)((man >> 1) & 1),
                            (float)(man & 1));
    float4* op = (float4*)(out + (size_t)idx * 8);
    op[0] = lo;
    op[1] = hi;
}

// ---------- branchless full E4M3 RNE quantizer for products ----------
// q(p) via magic add: quantum = max(2^(e-3), 2^-9) where e = binade(p).
// E = (p & 0x7f800000) as float == 2^e (0 for p==0/denorm-p, then floor
// kicks in via max). M = 1.5*2^20*max(E,2^-6) is an even multiple of the
// quantum, so (p+M)-M is RNE-to-quantum with correct ties-to-even for both
// signs; p+M stays inside M's binade (|p| < 2^(e+1) << M). t-M is exact
// (same binade, both multiples of quantum). Matches reference quant_e4m3
// (incl. subnormals and binade-top rounding) for all |p| << 448.
__device__ __forceinline__ float qprod(float x, float w) {
#pragma clang fp contract(off)
    float p  = x * w;                                 // exact (<=8 sig bits)
    float E  = __uint_as_float(__float_as_uint(p) & 0x7f800000u);
    float Ec = fmaxf(E, 0.015625f);                   // 2^-6 floor
    float M  = Ec * 1572864.0f;                       // 1.5 * 2^20 (exact)
    float t  = p + M;
    return t - M;
}

// ---------- serial-chain quantizer: 3-op Dekker (HW-proven in R7) ----------
// Valid for v = sum of two E4M3 values (multiple of 2^-9, so the subnormal
// region is already exact; normal region = round to 4 sig bits).
__device__ __forceinline__ float dek(float s) {
#pragma clang fp contract(off)
    float p1 = __builtin_fmaf(s, 1048576.0f, s);      // s*(2^20+1), RNE
    float d  = p1 - s;
    return p1 - d;
}

// ---------- main sequential-quantized accumulation ----------
// grid (B/4, OUT/64), block 256 = 4 waves; lane -> o, wave -> 1 b-row
// (unpacked scalar: 4096 waves = 4/SIMD for latency hiding of the serial
// chain). No fp8 cvt instructions anywhere (they issue at ~16 cyc; all ops
// here are full-rate 2-cyc scalar f32). x: block stages 4 rows in LDS,
// broadcast ds_read_b128, 1-group register prefetch. w: depth-4
// unconditional register prefetch, pointer-increment addressing.
__global__ __launch_bounds__(256) void k_main(const float* __restrict__ xf,
                                              const float* __restrict__ wt,
                                              float* __restrict__ out) {
    __shared__ float xs[4 * IN_DIM + 32];            // 8 KB + tail pad
    int tid  = threadIdx.x;
    int lane = tid & 63;
    int wid  = tid >> 6;
    int o = blockIdx.y * 64 + lane;
    int b = blockIdx.x * 4 + wid;

    // stage 4 contiguous x rows (2048 floats) coalesced
    {
        const float4* src = (const float4*)(xf + (size_t)blockIdx.x * 4 * IN_DIM);
        float4* dst = (float4*)xs;
        dst[tid]       = src[tid];
        dst[tid + 256] = src[tid + 256];
    }
    __syncthreads();

    const float4* xls = (const float4*)(xs + (size_t)wid * IN_DIM);  // 128 f4
    const float4* wq  = (const float4*)wt + o;       // stride OUT_DIM f4 per i4

    float acc = 0.0f;                                 // q(0 + p0) == p0

    // w slots hold groups 0..3 (slot d <- group d); group g = i4 {2g, 2g+1}
    float4 wA[4], wB[4];
    {
        const float4* wp = wq;
#pragma unroll
        for (int d = 0; d < 4; ++d) {
            wA[d] = wp[0];
            wB[d] = wp[OUT_DIM];
            wp += 2 * OUT_DIM;
        }
    }
    const float4* wqp = wq + (size_t)8 * OUT_DIM;    // next w prefetch: group 4

    // x: current group 0, prefetch pointer at group 1
    float4 xc0 = xls[0], xc1 = xls[1];
    const float4* xlp = xls + 2;

    for (int go = 0; go < 64; go += 4) {
#pragma unroll
        for (int ph = 0; ph < 4; ++ph) {
            // g = go + ph; slot ph holds group g; xc holds group g
            float4 xn0 = xlp[0], xn1 = xlp[1];        // prefetch group g+1
            xlp += 2;
            float4 cwA = wA[ph], cwB = wB[ph];
            wA[ph] = wqp[0];                          // prefetch w group g+4
            wB[ph] = wqp[OUT_DIM];
            wqp += 2 * OUT_DIM;

            float wk[8] = {cwA.x, cwA.y, cwA.z, cwA.w,
                           cwB.x, cwB.y, cwB.z, cwB.w};
            float xk[8] = {xc0.x, xc0.y, xc0.z, xc0.w,
                           xc1.x, xc1.y, xc1.z, xc1.w};
            float pf[8];
#pragma unroll
            for (int k = 0; k < 8; ++k)               // independent products
                pf[k] = qprod(xk[k], wk[k]);
#pragma unroll
            for (int k = 0; k < 8; ++k)               // serial chain
                acc = dek(acc + pf[k]);

            xc0 = xn0; xc1 = xn1;
        }
    }

    store8(out, b * OUT_DIM + o, acc);
}

extern "C" void kernel_launch(void* const* d_in, const int* in_sizes, int n_in,
                              void* d_out, int out_size, void* d_ws, size_t ws_size,
                              hipStream_t stream) {
    const float* xb = (const float*)d_in[0];   // [256][512][8]
    const float* wb = (const float*)d_in[1];   // [1024][512][8]
    float* out = (float*)d_out;                // [256][1024][8]

    float* xf = (float*)d_ws;                        // 131072 floats
    float* wt = (float*)d_ws + B_DIM * IN_DIM;       // 524288 floats
    // (w prefetch tail reads up to ~256 KB past wt end — ws is ~268 MB)

    int total = B_DIM * IN_DIM + OUT_DIM * IN_DIM;   // 655360
    k_decode<<<dim3(total / 256), dim3(256), 0, stream>>>(xb, wb, xf, wt);

    dim3 grid(B_DIM / 4, OUT_DIM / 64);
    k_main<<<grid, dim3(256), 0, stream>>>(xf, wt, out);
}